// Round 2
// 345.524 us; speedup vs baseline: 1.3310x; 1.3310x over previous
//
#include <hip/hip_runtime.h>
#include <utility>

// ---------------------------------------------------------------------------
// Compile-time generation of real-basis Wigner-3j tables (exact translation of
// the Python reference: _su2_cg, _q_real_to_complex, _w3j, normalized), then
// compile-time extraction of the sparse nonzero term list so phase 1 becomes a
// fully unrolled FMA chain with immediate coefficients (no table loads).
// ---------------------------------------------------------------------------
namespace w3j_gen {

struct FactT { double f[16]; };
constexpr FactT make_fact() {
    FactT t{}; t.f[0] = 1.0;
    for (int i = 1; i < 16; i++) t.f[i] = t.f[i-1] * (double)i;
    return t;
}
constexpr FactT FT = make_fact();

constexpr double csqrt(double x) {
    if (x <= 0.0) return 0.0;
    double g = x < 1.0 ? 1.0 : x;
    for (int i = 0; i < 80; i++) g = 0.5 * (g + x / g);
    return g;
}

constexpr int imax3(int a, int b, int c) { int m = a; if (b > m) m = b; if (c > m) m = c; return m; }
constexpr int imin3(int a, int b, int c) { int m = a; if (b < m) m = b; if (c < m) m = c; return m; }

constexpr double su2_cg(int j1, int m1, int j2, int m2, int j3, int m3) {
    if (m3 != m1 + m2) return 0.0;
    double pref = csqrt((double)(2*j3+1) * FT.f[j3+j1-j2] * FT.f[j3-j1+j2] * FT.f[j1+j2-j3] / FT.f[j1+j2+j3+1]);
    pref *= csqrt(FT.f[j3+m3] * FT.f[j3-m3] * FT.f[j1-m1] * FT.f[j1+m1] * FT.f[j2-m2] * FT.f[j2+m2]);
    int kmin = imax3(0, j2-j3-m1, j1-j3+m2);
    int kmax = imin3(j1+j2-j3, j1-m1, j2+m2);
    double s = 0.0;
    for (int k = kmin; k <= kmax; k++) {
        double d = FT.f[k] * FT.f[j1+j2-j3-k] * FT.f[j1-m1-k] * FT.f[j2+m2-k] * FT.f[j3-j2+m1+k] * FT.f[j3-j1-m2+k];
        s += ((k & 1) ? -1.0 : 1.0) / d;
    }
    return pref * s;
}

struct CD { double re, im; };
struct QT { CD q[7][7]; };

constexpr QT make_q(int l) {
    QT t{};
    const double is2 = csqrt(0.5);
    for (int m = -l; m < 0; m++) {
        t.q[l+m][l-m].re = is2;
        t.q[l+m][l+m].im = -is2;
    }
    t.q[l][l].re = 1.0;
    for (int m = 1; m <= l; m++) {
        double s = (m & 1) ? -1.0 : 1.0;
        t.q[l+m][l+m].re = s * is2;
        t.q[l+m][l-m].im = s * is2;
    }
    CD ph = {1.0, 0.0};
    if (l % 4 == 1) ph = {0.0, -1.0};
    else if (l % 4 == 2) ph = {-1.0, 0.0};
    else if (l % 4 == 3) ph = {0.0, 1.0};
    for (int i = 0; i < 7; i++)
        for (int j = 0; j < 7; j++) {
            CD a = t.q[i][j];
            t.q[i][j] = { ph.re*a.re - ph.im*a.im, ph.re*a.im + ph.im*a.re };
        }
    return t;
}

struct Tab { float v[245]; };

constexpr Tab make_w3j(int l1, int l2, int l3) {
    const int n1 = 2*l1+1, n2 = 2*l2+1, n3 = 2*l3+1;
    double C[7][7][7] = {};
    for (int m1 = -l1; m1 <= l1; m1++)
        for (int m2 = -l2; m2 <= l2; m2++) {
            int m3 = m1 + m2;
            if (m3 >= -l3 && m3 <= l3)
                C[l1+m1][l2+m2][l3+m3] = su2_cg(l1, m1, l2, m2, l3, m3);
        }
    QT Q1 = make_q(l1), Q2 = make_q(l2), Q3 = make_q(l3);
    CD T1[7][7][7] = {};
    for (int j = 0; j < n1; j++)
        for (int k = 0; k < n2; k++)
            for (int m = 0; m < n3; m++) {
                double sr = 0, si = 0;
                for (int i = 0; i < n1; i++) {
                    double cv = C[i][k][m];
                    sr += Q1.q[i][j].re * cv;
                    si += Q1.q[i][j].im * cv;
                }
                T1[j][k][m] = {sr, si};
            }
    CD T2[7][7][7] = {};
    for (int j = 0; j < n1; j++)
        for (int l = 0; l < n2; l++)
            for (int m = 0; m < n3; m++) {
                double sr = 0, si = 0;
                for (int k = 0; k < n2; k++) {
                    CD a = Q2.q[k][l], b = T1[j][k][m];
                    sr += a.re*b.re - a.im*b.im;
                    si += a.re*b.im + a.im*b.re;
                }
                T2[j][l][m] = {sr, si};
            }
    double Cr[7][7][7] = {};
    double nrm2 = 0.0;
    for (int j = 0; j < n1; j++)
        for (int l = 0; l < n2; l++)
            for (int n = 0; n < n3; n++) {
                double s = 0;
                for (int m = 0; m < n3; m++) {
                    CD a = Q3.q[n][m], b = T2[j][l][m];
                    s += a.re*b.re + a.im*b.im;
                }
                Cr[j][l][n] = s;
                nrm2 += s * s;
            }
    double inv = 1.0 / csqrt(nrm2);
    Tab t{};
    for (int j = 0; j < n1; j++)
        for (int l = 0; l < n2; l++)
            for (int n = 0; n < n3; n++)
                t.v[(j*n2 + l)*n3 + n] = (float)(Cr[j][l][n] * inv);
    return t;
}

// 23 unique keys, lo-major, (la,lb)-lexicographic within lo (matches path order).
constexpr Tab T0  = make_w3j(0,0,0);
constexpr Tab T1_ = make_w3j(1,1,0);
constexpr Tab T2_ = make_w3j(2,2,0);
constexpr Tab T3_ = make_w3j(3,3,0);
constexpr Tab T4  = make_w3j(0,1,1);
constexpr Tab T5  = make_w3j(1,0,1);
constexpr Tab T6  = make_w3j(1,2,1);
constexpr Tab T7  = make_w3j(2,1,1);
constexpr Tab T8  = make_w3j(2,3,1);
constexpr Tab T9  = make_w3j(3,2,1);
constexpr Tab T10 = make_w3j(0,2,2);
constexpr Tab T11 = make_w3j(1,1,2);
constexpr Tab T12 = make_w3j(1,3,2);
constexpr Tab T13 = make_w3j(2,0,2);
constexpr Tab T14 = make_w3j(2,2,2);
constexpr Tab T15 = make_w3j(3,1,2);
constexpr Tab T16 = make_w3j(3,3,2);
constexpr Tab T17 = make_w3j(0,3,3);
constexpr Tab T18 = make_w3j(1,2,3);
constexpr Tab T19 = make_w3j(2,1,3);
constexpr Tab T20 = make_w3j(2,3,3);
constexpr Tab T21 = make_w3j(3,0,3);
constexpr Tab T22 = make_w3j(3,2,3);

constexpr int KLA[23]   = {0,1,2,3, 0,1,1,2,2,3, 0,1,1,2,2,3,3, 0,1,2,2,3,3};
constexpr int KLB[23]   = {0,1,2,3, 1,0,2,1,3,2, 2,1,3,0,2,1,3, 3,2,1,3,0,2};
constexpr int KLO[23]   = {0,0,0,0, 1,1,1,1,1,1, 2,2,2,2,2,2,2, 3,3,3,3,3,3};
// z-slot layout identical to previous kernel: keys 0-3 -> 1 slot, 4-9 -> 3, 10-16 -> 5, 17-22 -> 7.
constexpr int KZOFF[23] = {0,1,2,3, 4,7,10,13,16,19, 22,27,32,37,42,47,52, 57,64,71,78,85,92};

struct Term { int i, j, k; float w; };
struct TermList { Term t[1875]; int koff[24]; int n; };

constexpr TermList build_terms() {
    TermList L{};
    const Tab* ts[23] = {&T0,&T1_,&T2_,&T3_,&T4,&T5,&T6,&T7,&T8,&T9,&T10,&T11,
                         &T12,&T13,&T14,&T15,&T16,&T17,&T18,&T19,&T20,&T21,&T22};
    for (int key = 0; key < 23; key++) {
        L.koff[key] = L.n;
        const int la = KLA[key], lb = KLB[key], lo = KLO[key];
        const int n1 = 2*la+1, n2 = 2*lb+1, n3 = 2*lo+1;
        for (int i = 0; i < n1; i++)
            for (int j = 0; j < n2; j++)
                for (int k = 0; k < n3; k++) {
                    float w = ts[key]->v[(i*n2+j)*n3+k];
                    float aw = w < 0 ? -w : w;
                    if (aw > 1e-6f) {
                        L.t[L.n].i = la*la + i;
                        L.t[L.n].j = lb*lb + j;
                        L.t[L.n].k = KZOFF[key] + k;
                        L.t[L.n].w = w;
                        L.n++;
                    }
                }
    }
    L.koff[23] = L.n;
    return L;
}
constexpr TermList TL = build_terms();

} // namespace w3j_gen

// --- compile-time-unrolled sparse bilinear: per key, accumulate in registers,
// --- flush to the LDS z-row (all indices/coefs are compile-time constants).
template <int KEY, size_t... I>
__device__ __forceinline__ void term_unroll(float* __restrict__ acc,
                                            const float* __restrict__ xv,
                                            const float* __restrict__ yv,
                                            std::index_sequence<I...>) {
    constexpr int t0 = w3j_gen::TL.koff[KEY];
    ((acc[w3j_gen::TL.t[t0 + I].k - w3j_gen::KZOFF[KEY]] +=
          w3j_gen::TL.t[t0 + I].w * xv[w3j_gen::TL.t[t0 + I].i] * yv[w3j_gen::TL.t[t0 + I].j]), ...);
}

template <int KEY>
__device__ __forceinline__ void key_accum(float* __restrict__ zrow,
                                          const float* __restrict__ xv,
                                          const float* __restrict__ yv) {
    constexpr int n3 = 2 * w3j_gen::KLO[KEY] + 1;
    constexpr int nt = w3j_gen::TL.koff[KEY + 1] - w3j_gen::TL.koff[KEY];
    float acc[n3] = {};
    term_unroll<KEY>(acc, xv, yv, std::make_index_sequence<(size_t)nt>{});
    #pragma unroll
    for (int k = 0; k < n3; k++) zrow[w3j_gen::KZOFF[KEY] + k] = acc[k];
}

template <size_t... K>
__device__ __forceinline__ void all_keys(float* __restrict__ zrow,
                                         const float* __restrict__ xv,
                                         const float* __restrict__ yv,
                                         std::index_sequence<K...>) {
    (key_accum<(int)K>(zrow, xv, yv), ...);
}

#define N_EDGES   65536
#define TILE      64
#define ZROW      108                 // padded row (16B-aligned stride, room for c<16 predicated reads)
#define ALL_BASE  75497472ull         // 65536 * 9 * 128

__device__ __forceinline__ float sigmoidf_(float v) { return 1.0f / (1.0f + __expf(-v)); }

__global__ __launch_bounds__(256)
void cg_interaction_kernel(
    const float* __restrict__ x, const float* __restrict__ y,
    const float* __restrict__ w_cg, const float* __restrict__ b_cg,
    const float* __restrict__ w_all, const float* __restrict__ b_all,
    float* __restrict__ out)
{
    __shared__ __align__(16) float zs[TILE][ZROW];   // 27.6 KB

    const int tid = threadIdx.x;
    const int e0 = blockIdx.x * TILE;

    // ---- Phase 1: one thread per edge, fully unrolled sparse z computation ----
    if (tid < TILE) {
        const int e = e0 + tid;
        float xv[16], yv[16];
        const float4* xp = (const float4*)(x + (size_t)e * 16);
        const float4* yp = (const float4*)(y + (size_t)e * 16);
        #pragma unroll
        for (int q = 0; q < 4; q++) {
            float4 v = xp[q];
            xv[4*q+0] = v.x; xv[4*q+1] = v.y; xv[4*q+2] = v.z; xv[4*q+3] = v.w;
            float4 u = yp[q];
            yv[4*q+0] = u.x; yv[4*q+1] = u.y; yv[4*q+2] = u.z; yv[4*q+3] = u.w;
        }
        all_keys(&zs[tid][0], xv, yv, std::make_index_sequence<23>{});
    }
    __syncthreads();

    // ---- Phase 2: 2 halves x 128 channels; weights hoisted over 32 edges ----
    const int half = tid >> 7;
    const int c = tid & 127;

    float wc0[4], wc1[4], wc2[4];
    #pragma unroll
    for (int p = 0; p < 4; p++) {
        wc0[p] = w_cg[p * 128 + c];
        wc1[p] = w_cg[512 + p * 256 + c];
        wc2[p] = w_cg[640 + p * 256 + c];
    }
    float wl1[6];
    #pragma unroll
    for (int p = 0; p < 6; p++) wl1[p] = w_cg[1536 + p * 128 + c];
    float wl2[7];
    #pragma unroll
    for (int p = 0; p < 7; p++) wl2[p] = w_cg[2304 + p * 128 + c];
    const float b0 = b_cg[c], b1 = b_cg[128 + c], b2 = b_cg[256 + c];

    const float SQ12 = 0.70710678118654752f;   // sqrt(3/6)
    const float SQ57 = 0.84515425472851657f;   // sqrt(5/7)
    const float SQ76 = 1.08012344973464f;      // sqrt(7/6)

    // cg_all per-lane setup (lanes c<16 only; zeros elsewhere keep it safe)
    float gw0 = 0.f, gw1 = 0.f, gw2 = 0.f, gw3 = 0.f, gb = 0.f, ascale = 0.f;
    int zbase = 4, zstride = 3;
    float aw[7] = {0.f,0.f,0.f,0.f,0.f,0.f,0.f};
    if (c == 0) {
        gw0 = w_all[0]; gw1 = w_all[1]; gw2 = w_all[2]; gw3 = w_all[3]; gb = b_all[0];
    } else if (c < 4) {
        gw0 = w_all[4]; gw1 = w_all[7]; gw2 = w_all[10]; gw3 = w_all[13]; gb = b_all[1];
        ascale = SQ12; zbase = 4 + (c - 1); zstride = 3;
        #pragma unroll
        for (int p = 0; p < 6; p++) aw[p] = w_all[16 + p];
    } else if (c < 9) {
        gw0 = w_all[5]; gw1 = w_all[8]; gw2 = w_all[11]; gw3 = w_all[14]; gb = b_all[2];
        ascale = SQ57; zbase = 22 + (c - 4); zstride = 5;
        #pragma unroll
        for (int p = 0; p < 7; p++) aw[p] = w_all[22 + p];
    } else if (c < 16) {
        gw0 = w_all[6]; gw1 = w_all[9]; gw2 = w_all[12]; gw3 = w_all[15]; gb = b_all[3];
        ascale = SQ76; zbase = 57 + (c - 9); zstride = 7;
        #pragma unroll
        for (int p = 0; p < 6; p++) aw[p] = w_all[29 + p];
    }

    for (int t = half; t < TILE; t += 2) {
        const size_t e = (size_t)(e0 + t);
        const float* zrow = &zs[t][0];

        // broadcast-load z[0..59] into registers (compile-time indices -> VGPRs)
        float zz[60];
        #pragma unroll
        for (int q = 0; q < 15; q++) {
            float4 v = *(const float4*)(zrow + 4 * q);
            zz[4*q+0] = v.x; zz[4*q+1] = v.y; zz[4*q+2] = v.z; zz[4*q+3] = v.w;
        }

        float u0 = (zz[0]*wc0[0] + zz[1]*wc0[1] + zz[2]*wc0[2] + zz[3]*wc0[3]) * 0.5f + b0;
        float u1 = (zz[0]*wc1[0] + zz[1]*wc1[1] + zz[2]*wc1[2] + zz[3]*wc1[3]) * 0.5f + b1;
        float u2 = (zz[0]*wc2[0] + zz[1]*wc2[1] + zz[2]*wc2[2] + zz[3]*wc2[3]) * 0.5f + b2;
        float sc = u0 * sigmoidf_(u0);
        float g1 = sigmoidf_(u1) * SQ12;
        float g2 = sigmoidf_(u2) * SQ57;

        float* o = out + e * 1152 + c;
        __builtin_nontemporal_store(sc, o);
        #pragma unroll
        for (int k = 0; k < 3; k++) {
            float s = 0.0f;
            #pragma unroll
            for (int p = 0; p < 6; p++) s += zz[4 + 3*p + k] * wl1[p];
            __builtin_nontemporal_store(s * g1, o + (1 + k) * 128);
        }
        #pragma unroll
        for (int k = 0; k < 5; k++) {
            float s = 0.0f;
            #pragma unroll
            for (int p = 0; p < 7; p++) s += zz[22 + 5*p + k] * wl2[p];
            __builtin_nontemporal_store(s * g2, o + (4 + k) * 128);
        }

        if (c < 16) {
            float g = (zz[0]*gw0 + zz[1]*gw1 + zz[2]*gw2 + zz[3]*gw3) * 0.5f + gb;
            float v;
            if (c == 0) {
                v = g * sigmoidf_(g);
            } else {
                float s = 0.0f;
                #pragma unroll
                for (int p = 0; p < 7; p++) {
                    float zv = zrow[zbase + zstride * p];   // runtime index stays in LDS (no scratch)
                    s += aw[p] * zv;
                }
                v = s * ascale * sigmoidf_(g);
            }
            __builtin_nontemporal_store(v, out + ALL_BASE + e * 16 + c);
        }
    }
}

extern "C" void kernel_launch(void* const* d_in, const int* in_sizes, int n_in,
                              void* d_out, int out_size, void* d_ws, size_t ws_size,
                              hipStream_t stream) {
    const float* x     = (const float*)d_in[0];
    const float* y     = (const float*)d_in[1];
    const float* w_cg  = (const float*)d_in[2];
    const float* b_cg  = (const float*)d_in[3];
    const float* w_all = (const float*)d_in[4];
    const float* b_all = (const float*)d_in[5];
    float* out = (float*)d_out;

    dim3 grid(N_EDGES / TILE), block(256);
    hipLaunchKernelGGL(cg_interaction_kernel, grid, block, 0, stream,
                       x, y, w_cg, b_cg, w_all, b_all, out);
}

// Round 4
// 333.385 us; speedup vs baseline: 1.3795x; 1.0364x over previous
//
#include <hip/hip_runtime.h>
#include <utility>

// ---------------------------------------------------------------------------
// Compile-time generation of real-basis Wigner-3j tables (exact translation of
// the Python reference: _su2_cg, _q_real_to_complex, _w3j, normalized), then
// compile-time extraction of the sparse nonzero term list so phase 1 becomes a
// fully unrolled FMA chain with immediate coefficients (no table loads).
// ---------------------------------------------------------------------------
namespace w3j_gen {

struct FactT { double f[16]; };
constexpr FactT make_fact() {
    FactT t{}; t.f[0] = 1.0;
    for (int i = 1; i < 16; i++) t.f[i] = t.f[i-1] * (double)i;
    return t;
}
constexpr FactT FT = make_fact();

constexpr double csqrt(double x) {
    if (x <= 0.0) return 0.0;
    double g = x < 1.0 ? 1.0 : x;
    for (int i = 0; i < 80; i++) g = 0.5 * (g + x / g);
    return g;
}

constexpr int imax3(int a, int b, int c) { int m = a; if (b > m) m = b; if (c > m) m = c; return m; }
constexpr int imin3(int a, int b, int c) { int m = a; if (b < m) m = b; if (c < m) m = c; return m; }

constexpr double su2_cg(int j1, int m1, int j2, int m2, int j3, int m3) {
    if (m3 != m1 + m2) return 0.0;
    double pref = csqrt((double)(2*j3+1) * FT.f[j3+j1-j2] * FT.f[j3-j1+j2] * FT.f[j1+j2-j3] / FT.f[j1+j2+j3+1]);
    pref *= csqrt(FT.f[j3+m3] * FT.f[j3-m3] * FT.f[j1-m1] * FT.f[j1+m1] * FT.f[j2-m2] * FT.f[j2+m2]);
    int kmin = imax3(0, j2-j3-m1, j1-j3+m2);
    int kmax = imin3(j1+j2-j3, j1-m1, j2+m2);
    double s = 0.0;
    for (int k = kmin; k <= kmax; k++) {
        double d = FT.f[k] * FT.f[j1+j2-j3-k] * FT.f[j1-m1-k] * FT.f[j2+m2-k] * FT.f[j3-j2+m1+k] * FT.f[j3-j1-m2+k];
        s += ((k & 1) ? -1.0 : 1.0) / d;
    }
    return pref * s;
}

struct CD { double re, im; };
struct QT { CD q[7][7]; };

constexpr QT make_q(int l) {
    QT t{};
    const double is2 = csqrt(0.5);
    for (int m = -l; m < 0; m++) {
        t.q[l+m][l-m].re = is2;
        t.q[l+m][l+m].im = -is2;
    }
    t.q[l][l].re = 1.0;
    for (int m = 1; m <= l; m++) {
        double s = (m & 1) ? -1.0 : 1.0;
        t.q[l+m][l+m].re = s * is2;
        t.q[l+m][l-m].im = s * is2;
    }
    CD ph = {1.0, 0.0};
    if (l % 4 == 1) ph = {0.0, -1.0};
    else if (l % 4 == 2) ph = {-1.0, 0.0};
    else if (l % 4 == 3) ph = {0.0, 1.0};
    for (int i = 0; i < 7; i++)
        for (int j = 0; j < 7; j++) {
            CD a = t.q[i][j];
            t.q[i][j] = { ph.re*a.re - ph.im*a.im, ph.re*a.im + ph.im*a.re };
        }
    return t;
}

struct Tab { float v[245]; };

constexpr Tab make_w3j(int l1, int l2, int l3) {
    const int n1 = 2*l1+1, n2 = 2*l2+1, n3 = 2*l3+1;
    double C[7][7][7] = {};
    for (int m1 = -l1; m1 <= l1; m1++)
        for (int m2 = -l2; m2 <= l2; m2++) {
            int m3 = m1 + m2;
            if (m3 >= -l3 && m3 <= l3)
                C[l1+m1][l2+m2][l3+m3] = su2_cg(l1, m1, l2, m2, l3, m3);
        }
    QT Q1 = make_q(l1), Q2 = make_q(l2), Q3 = make_q(l3);
    CD T1[7][7][7] = {};
    for (int j = 0; j < n1; j++)
        for (int k = 0; k < n2; k++)
            for (int m = 0; m < n3; m++) {
                double sr = 0, si = 0;
                for (int i = 0; i < n1; i++) {
                    double cv = C[i][k][m];
                    sr += Q1.q[i][j].re * cv;
                    si += Q1.q[i][j].im * cv;
                }
                T1[j][k][m] = {sr, si};
            }
    CD T2[7][7][7] = {};
    for (int j = 0; j < n1; j++)
        for (int l = 0; l < n2; l++)
            for (int m = 0; m < n3; m++) {
                double sr = 0, si = 0;
                for (int k = 0; k < n2; k++) {
                    CD a = Q2.q[k][l], b = T1[j][k][m];
                    sr += a.re*b.re - a.im*b.im;
                    si += a.re*b.im + a.im*b.re;
                }
                T2[j][l][m] = {sr, si};
            }
    double Cr[7][7][7] = {};
    double nrm2 = 0.0;
    for (int j = 0; j < n1; j++)
        for (int l = 0; l < n2; l++)
            for (int n = 0; n < n3; n++) {
                double s = 0;
                for (int m = 0; m < n3; m++) {
                    CD a = Q3.q[n][m], b = T2[j][l][m];
                    s += a.re*b.re + a.im*b.im;
                }
                Cr[j][l][n] = s;
                nrm2 += s * s;
            }
    double inv = 1.0 / csqrt(nrm2);
    Tab t{};
    for (int j = 0; j < n1; j++)
        for (int l = 0; l < n2; l++)
            for (int n = 0; n < n3; n++)
                t.v[(j*n2 + l)*n3 + n] = (float)(Cr[j][l][n] * inv);
    return t;
}

// 23 unique keys, lo-major, (la,lb)-lexicographic within lo (matches path order).
constexpr Tab T0  = make_w3j(0,0,0);
constexpr Tab T1_ = make_w3j(1,1,0);
constexpr Tab T2_ = make_w3j(2,2,0);
constexpr Tab T3_ = make_w3j(3,3,0);
constexpr Tab T4  = make_w3j(0,1,1);
constexpr Tab T5  = make_w3j(1,0,1);
constexpr Tab T6  = make_w3j(1,2,1);
constexpr Tab T7  = make_w3j(2,1,1);
constexpr Tab T8  = make_w3j(2,3,1);
constexpr Tab T9  = make_w3j(3,2,1);
constexpr Tab T10 = make_w3j(0,2,2);
constexpr Tab T11 = make_w3j(1,1,2);
constexpr Tab T12 = make_w3j(1,3,2);
constexpr Tab T13 = make_w3j(2,0,2);
constexpr Tab T14 = make_w3j(2,2,2);
constexpr Tab T15 = make_w3j(3,1,2);
constexpr Tab T16 = make_w3j(3,3,2);
constexpr Tab T17 = make_w3j(0,3,3);
constexpr Tab T18 = make_w3j(1,2,3);
constexpr Tab T19 = make_w3j(2,1,3);
constexpr Tab T20 = make_w3j(2,3,3);
constexpr Tab T21 = make_w3j(3,0,3);
constexpr Tab T22 = make_w3j(3,2,3);

constexpr int KLA[23]   = {0,1,2,3, 0,1,1,2,2,3, 0,1,1,2,2,3,3, 0,1,2,2,3,3};
constexpr int KLB[23]   = {0,1,2,3, 1,0,2,1,3,2, 2,1,3,0,2,1,3, 3,2,1,3,0,2};
constexpr int KLO[23]   = {0,0,0,0, 1,1,1,1,1,1, 2,2,2,2,2,2,2, 3,3,3,3,3,3};
// z-slot layout: keys 0-3 -> 1 slot, 4-9 -> 3, 10-16 -> 5, 17-22 -> 7.
constexpr int KZOFF[23] = {0,1,2,3, 4,7,10,13,16,19, 22,27,32,37,42,47,52, 57,64,71,78,85,92};

struct Term { int i, j, k; float w; };
struct TermList { Term t[1875]; int koff[24]; int n; };

constexpr TermList build_terms() {
    TermList L{};
    const Tab* ts[23] = {&T0,&T1_,&T2_,&T3_,&T4,&T5,&T6,&T7,&T8,&T9,&T10,&T11,
                         &T12,&T13,&T14,&T15,&T16,&T17,&T18,&T19,&T20,&T21,&T22};
    for (int key = 0; key < 23; key++) {
        L.koff[key] = L.n;
        const int la = KLA[key], lb = KLB[key], lo = KLO[key];
        const int n1 = 2*la+1, n2 = 2*lb+1, n3 = 2*lo+1;
        for (int i = 0; i < n1; i++)
            for (int j = 0; j < n2; j++)
                for (int k = 0; k < n3; k++) {
                    float w = ts[key]->v[(i*n2+j)*n3+k];
                    float aw = w < 0 ? -w : w;
                    if (aw > 1e-6f) {
                        L.t[L.n].i = la*la + i;
                        L.t[L.n].j = lb*lb + j;
                        L.t[L.n].k = KZOFF[key] + k;
                        L.t[L.n].w = w;
                        L.n++;
                    }
                }
    }
    L.koff[23] = L.n;
    return L;
}
constexpr TermList TL = build_terms();

// 4-way key-range split, balanced by term count (key granularity). Each wave
// of phase 1 executes one range; key z-slots are disjoint, so no reduction.
constexpr int find_split(int target) {
    for (int k = 0; k <= 23; k++) if (TL.koff[k] >= target) return k;
    return 23;
}
constexpr int S1 = find_split(TL.n / 4);
constexpr int S2 = find_split(TL.n / 2);
constexpr int S3 = find_split(3 * TL.n / 4);

} // namespace w3j_gen

// --- compile-time-unrolled sparse bilinear: per key, accumulate in registers,
// --- flush to the LDS z-row (all indices/coefs are compile-time constants).
template <int KEY, size_t... I>
__device__ __forceinline__ void term_unroll(float* __restrict__ acc,
                                            const float* __restrict__ xv,
                                            const float* __restrict__ yv,
                                            std::index_sequence<I...>) {
    constexpr int t0 = w3j_gen::TL.koff[KEY];
    ((acc[w3j_gen::TL.t[t0 + I].k - w3j_gen::KZOFF[KEY]] +=
          w3j_gen::TL.t[t0 + I].w * xv[w3j_gen::TL.t[t0 + I].i] * yv[w3j_gen::TL.t[t0 + I].j]), ...);
}

template <int KEY>
__device__ __forceinline__ void key_accum(float* __restrict__ zrow,
                                          const float* __restrict__ xv,
                                          const float* __restrict__ yv) {
    constexpr int n3 = 2 * w3j_gen::KLO[KEY] + 1;
    constexpr int nt = w3j_gen::TL.koff[KEY + 1] - w3j_gen::TL.koff[KEY];
    float acc[n3] = {};
    term_unroll<KEY>(acc, xv, yv, std::make_index_sequence<(size_t)nt>{});
    #pragma unroll
    for (int k = 0; k < n3; k++) zrow[w3j_gen::KZOFF[KEY] + k] = acc[k];
}

template <int FROM, size_t... K>
__device__ __forceinline__ void keys_range(float* __restrict__ zrow,
                                           const float* __restrict__ xv,
                                           const float* __restrict__ yv,
                                           std::index_sequence<K...>) {
    (key_accum<FROM + (int)K>(zrow, xv, yv), ...);
}

#define N_EDGES   65536
#define TILE      64
#define ZROW      108                 // padded row stride (16B-aligned)
#define ALL_BASE  75497472ull         // 65536 * 9 * 128

typedef float f32x4 __attribute__((ext_vector_type(4)));   // clang vector: valid for nontemporal builtins

__device__ __forceinline__ float sigmoidf_(float v) { return 1.0f / (1.0f + __expf(-v)); }

__global__ __launch_bounds__(256, 2)
void cg_interaction_kernel(
    const float* __restrict__ x, const float* __restrict__ y,
    const float* __restrict__ w_cg, const float* __restrict__ b_cg,
    const float* __restrict__ w_all, const float* __restrict__ b_all,
    float* __restrict__ out)
{
    __shared__ __align__(16) float zs[TILE][ZROW];   // 27.6 KB

    const int tid = threadIdx.x;
    const int e0 = blockIdx.x * TILE;

    // ---- Phase 1: 4 waves x 64 edges; each wave does ~1/4 of the term list ----
    {
        const int eidx = tid & 63;        // edge within tile
        const int esub = tid >> 6;        // wave id -> key-range
        float xv[16], yv[16];
        const float4* xp = (const float4*)(x + (size_t)(e0 + eidx) * 16);
        const float4* yp = (const float4*)(y + (size_t)(e0 + eidx) * 16);
        #pragma unroll
        for (int q = 0; q < 4; q++) {
            float4 v = xp[q];
            xv[4*q+0] = v.x; xv[4*q+1] = v.y; xv[4*q+2] = v.z; xv[4*q+3] = v.w;
            float4 u = yp[q];
            yv[4*q+0] = u.x; yv[4*q+1] = u.y; yv[4*q+2] = u.z; yv[4*q+3] = u.w;
        }
        using namespace w3j_gen;
        float* zrow = &zs[eidx][0];
        if (esub == 0)      keys_range<0 >(zrow, xv, yv, std::make_index_sequence<S1>{});
        else if (esub == 1) keys_range<S1>(zrow, xv, yv, std::make_index_sequence<S2 - S1>{});
        else if (esub == 2) keys_range<S2>(zrow, xv, yv, std::make_index_sequence<S3 - S2>{});
        else                keys_range<S3>(zrow, xv, yv, std::make_index_sequence<23 - S3>{});
    }
    __syncthreads();

    // ---- Phase 2: 32 channel-quads x 8 edge-slots; float4 weight loads+stores ----
    const int cq = (tid & 31) << 2;   // channel base: 0,4,...,124
    const int es = tid >> 5;          // edge slot 0..7

    float w00[4][4], wg1[4][4], wg2[4][4];
    #pragma unroll
    for (int p = 0; p < 4; p++) {
        float4 a = *(const float4*)(w_cg + p * 128 + cq);
        w00[p][0]=a.x; w00[p][1]=a.y; w00[p][2]=a.z; w00[p][3]=a.w;
        float4 b = *(const float4*)(w_cg + 512 + p * 256 + cq);
        wg1[p][0]=b.x; wg1[p][1]=b.y; wg1[p][2]=b.z; wg1[p][3]=b.w;
        float4 d = *(const float4*)(w_cg + 640 + p * 256 + cq);
        wg2[p][0]=d.x; wg2[p][1]=d.y; wg2[p][2]=d.z; wg2[p][3]=d.w;
    }
    float wl1[6][4];
    #pragma unroll
    for (int p = 0; p < 6; p++) {
        float4 a = *(const float4*)(w_cg + 1536 + p * 128 + cq);
        wl1[p][0]=a.x; wl1[p][1]=a.y; wl1[p][2]=a.z; wl1[p][3]=a.w;
    }
    float wl2[7][4];
    #pragma unroll
    for (int p = 0; p < 7; p++) {
        float4 a = *(const float4*)(w_cg + 2304 + p * 128 + cq);
        wl2[p][0]=a.x; wl2[p][1]=a.y; wl2[p][2]=a.z; wl2[p][3]=a.w;
    }
    float b0[4], b1[4], b2[4];
    {
        float4 a = *(const float4*)(b_cg + cq);
        b0[0]=a.x; b0[1]=a.y; b0[2]=a.z; b0[3]=a.w;
        float4 b = *(const float4*)(b_cg + 128 + cq);
        b1[0]=b.x; b1[1]=b.y; b1[2]=b.z; b1[3]=b.w;
        float4 d = *(const float4*)(b_cg + 256 + cq);
        b2[0]=d.x; b2[1]=d.y; b2[2]=d.z; b2[3]=d.w;
    }

    const float SQ12 = 0.70710678118654752f;   // sqrt(3/6)
    const float SQ57 = 0.84515425472851657f;   // sqrt(5/7)

    float* o = out + (size_t)(e0 + es) * 1152 + cq;
    for (int t = es; t < TILE; t += 8, o += 8 * 1152) {
        const float* zrow = &zs[t][0];
        float zz[60];
        #pragma unroll
        for (int q = 0; q < 15; q++) {
            float4 v = *(const float4*)(zrow + 4 * q);
            zz[4*q+0] = v.x; zz[4*q+1] = v.y; zz[4*q+2] = v.z; zz[4*q+3] = v.w;
        }

        float sc[4], g1[4], g2[4];
        #pragma unroll
        for (int j = 0; j < 4; j++) {
            float u0 = (zz[0]*w00[0][j] + zz[1]*w00[1][j] + zz[2]*w00[2][j] + zz[3]*w00[3][j]) * 0.5f + b0[j];
            float u1 = (zz[0]*wg1[0][j] + zz[1]*wg1[1][j] + zz[2]*wg1[2][j] + zz[3]*wg1[3][j]) * 0.5f + b1[j];
            float u2 = (zz[0]*wg2[0][j] + zz[1]*wg2[1][j] + zz[2]*wg2[2][j] + zz[3]*wg2[3][j]) * 0.5f + b2[j];
            sc[j] = u0 * sigmoidf_(u0);
            g1[j] = sigmoidf_(u1) * SQ12;
            g2[j] = sigmoidf_(u2) * SQ57;
        }

        f32x4 r0 = { sc[0], sc[1], sc[2], sc[3] };
        __builtin_nontemporal_store(r0, (f32x4*)o);
        #pragma unroll
        for (int k = 0; k < 3; k++) {
            float s[4];
            #pragma unroll
            for (int j = 0; j < 4; j++) {
                float a = 0.0f;
                #pragma unroll
                for (int p = 0; p < 6; p++) a += zz[4 + 3*p + k] * wl1[p][j];
                s[j] = a * g1[j];
            }
            f32x4 r = { s[0], s[1], s[2], s[3] };
            __builtin_nontemporal_store(r, (f32x4*)(o + (1 + k) * 128));
        }
        #pragma unroll
        for (int k = 0; k < 5; k++) {
            float s[4];
            #pragma unroll
            for (int j = 0; j < 4; j++) {
                float a = 0.0f;
                #pragma unroll
                for (int p = 0; p < 7; p++) a += zz[22 + 5*p + k] * wl2[p][j];
                s[j] = a * g2[j];
            }
            f32x4 r = { s[0], s[1], s[2], s[3] };
            __builtin_nontemporal_store(r, (f32x4*)(o + (4 + k) * 128));
        }
    }

    // ---- cg_all tail: 16 outputs/edge, threads 0..127 (c = tid&15, 8 edge-slots) ----
    if (tid < 128) {
        const int c = tid & 15;
        const int es2 = tid >> 4;     // 0..7
        const float SQ76 = 1.08012344973464f;  // sqrt(7/6)

        if (c == 0) {
            const float gw0 = w_all[0], gw1 = w_all[1], gw2 = w_all[2], gw3 = w_all[3], gb = b_all[0];
            for (int t = es2; t < TILE; t += 8) {
                const float* zr = &zs[t][0];
                float g = (zr[0]*gw0 + zr[1]*gw1 + zr[2]*gw2 + zr[3]*gw3) * 0.5f + gb;
                __builtin_nontemporal_store(g * sigmoidf_(g), out + ALL_BASE + (size_t)(e0 + t) * 16);
            }
        } else if (c < 4) {
            const float gw0 = w_all[4], gw1 = w_all[7], gw2 = w_all[10], gw3 = w_all[13], gb = b_all[1];
            float aw[6];
            #pragma unroll
            for (int p = 0; p < 6; p++) aw[p] = w_all[16 + p];
            const int zb = 4 + (c - 1);
            for (int t = es2; t < TILE; t += 8) {
                const float* zr = &zs[t][0];
                float g = (zr[0]*gw0 + zr[1]*gw1 + zr[2]*gw2 + zr[3]*gw3) * 0.5f + gb;
                float s = 0.0f;
                #pragma unroll
                for (int p = 0; p < 6; p++) s += aw[p] * zr[zb + 3*p];
                __builtin_nontemporal_store(s * SQ12 * sigmoidf_(g),
                                            out + ALL_BASE + (size_t)(e0 + t) * 16 + c);
            }
        } else if (c < 9) {
            const float gw0 = w_all[5], gw1 = w_all[8], gw2 = w_all[11], gw3 = w_all[14], gb = b_all[2];
            float aw[7];
            #pragma unroll
            for (int p = 0; p < 7; p++) aw[p] = w_all[22 + p];
            const int zb = 22 + (c - 4);
            for (int t = es2; t < TILE; t += 8) {
                const float* zr = &zs[t][0];
                float g = (zr[0]*gw0 + zr[1]*gw1 + zr[2]*gw2 + zr[3]*gw3) * 0.5f + gb;
                float s = 0.0f;
                #pragma unroll
                for (int p = 0; p < 7; p++) s += aw[p] * zr[zb + 5*p];
                __builtin_nontemporal_store(s * SQ57 * sigmoidf_(g),
                                            out + ALL_BASE + (size_t)(e0 + t) * 16 + c);
            }
        } else {
            const float gw0 = w_all[6], gw1 = w_all[9], gw2 = w_all[12], gw3 = w_all[15], gb = b_all[3];
            float aw[6];
            #pragma unroll
            for (int p = 0; p < 6; p++) aw[p] = w_all[29 + p];
            const int zb = 57 + (c - 9);
            for (int t = es2; t < TILE; t += 8) {
                const float* zr = &zs[t][0];
                float g = (zr[0]*gw0 + zr[1]*gw1 + zr[2]*gw2 + zr[3]*gw3) * 0.5f + gb;
                float s = 0.0f;
                #pragma unroll
                for (int p = 0; p < 6; p++) s += aw[p] * zr[zb + 7*p];
                __builtin_nontemporal_store(s * SQ76 * sigmoidf_(g),
                                            out + ALL_BASE + (size_t)(e0 + t) * 16 + c);
            }
        }
    }
}

extern "C" void kernel_launch(void* const* d_in, const int* in_sizes, int n_in,
                              void* d_out, int out_size, void* d_ws, size_t ws_size,
                              hipStream_t stream) {
    const float* x     = (const float*)d_in[0];
    const float* y     = (const float*)d_in[1];
    const float* w_cg  = (const float*)d_in[2];
    const float* b_cg  = (const float*)d_in[3];
    const float* w_all = (const float*)d_in[4];
    const float* b_all = (const float*)d_in[5];
    float* out = (float*)d_out;

    dim3 grid(N_EDGES / TILE), block(256);
    hipLaunchKernelGGL(cg_interaction_kernel, grid, block, 0, stream,
                       x, y, w_cg, b_cg, w_all, b_all, out);
}

// Round 5
// 330.467 us; speedup vs baseline: 1.3916x; 1.0088x over previous
//
#include <hip/hip_runtime.h>
#include <utility>

// ---------------------------------------------------------------------------
// Compile-time generation of real-basis Wigner-3j tables (exact translation of
// the Python reference: _su2_cg, _q_real_to_complex, _w3j, normalized), then
// compile-time extraction of the sparse nonzero term list so phase 1 becomes a
// fully unrolled FMA chain with immediate coefficients (no table loads).
// ---------------------------------------------------------------------------
namespace w3j_gen {

struct FactT { double f[16]; };
constexpr FactT make_fact() {
    FactT t{}; t.f[0] = 1.0;
    for (int i = 1; i < 16; i++) t.f[i] = t.f[i-1] * (double)i;
    return t;
}
constexpr FactT FT = make_fact();

constexpr double csqrt(double x) {
    if (x <= 0.0) return 0.0;
    double g = x < 1.0 ? 1.0 : x;
    for (int i = 0; i < 80; i++) g = 0.5 * (g + x / g);
    return g;
}

constexpr int imax3(int a, int b, int c) { int m = a; if (b > m) m = b; if (c > m) m = c; return m; }
constexpr int imin3(int a, int b, int c) { int m = a; if (b < m) m = b; if (c < m) m = c; return m; }

constexpr double su2_cg(int j1, int m1, int j2, int m2, int j3, int m3) {
    if (m3 != m1 + m2) return 0.0;
    double pref = csqrt((double)(2*j3+1) * FT.f[j3+j1-j2] * FT.f[j3-j1+j2] * FT.f[j1+j2-j3] / FT.f[j1+j2+j3+1]);
    pref *= csqrt(FT.f[j3+m3] * FT.f[j3-m3] * FT.f[j1-m1] * FT.f[j1+m1] * FT.f[j2-m2] * FT.f[j2+m2]);
    int kmin = imax3(0, j2-j3-m1, j1-j3+m2);
    int kmax = imin3(j1+j2-j3, j1-m1, j2+m2);
    double s = 0.0;
    for (int k = kmin; k <= kmax; k++) {
        double d = FT.f[k] * FT.f[j1+j2-j3-k] * FT.f[j1-m1-k] * FT.f[j2+m2-k] * FT.f[j3-j2+m1+k] * FT.f[j3-j1-m2+k];
        s += ((k & 1) ? -1.0 : 1.0) / d;
    }
    return pref * s;
}

struct CD { double re, im; };
struct QT { CD q[7][7]; };

constexpr QT make_q(int l) {
    QT t{};
    const double is2 = csqrt(0.5);
    for (int m = -l; m < 0; m++) {
        t.q[l+m][l-m].re = is2;
        t.q[l+m][l+m].im = -is2;
    }
    t.q[l][l].re = 1.0;
    for (int m = 1; m <= l; m++) {
        double s = (m & 1) ? -1.0 : 1.0;
        t.q[l+m][l+m].re = s * is2;
        t.q[l+m][l-m].im = s * is2;
    }
    CD ph = {1.0, 0.0};
    if (l % 4 == 1) ph = {0.0, -1.0};
    else if (l % 4 == 2) ph = {-1.0, 0.0};
    else if (l % 4 == 3) ph = {0.0, 1.0};
    for (int i = 0; i < 7; i++)
        for (int j = 0; j < 7; j++) {
            CD a = t.q[i][j];
            t.q[i][j] = { ph.re*a.re - ph.im*a.im, ph.re*a.im + ph.im*a.re };
        }
    return t;
}

struct Tab { float v[245]; };

constexpr Tab make_w3j(int l1, int l2, int l3) {
    const int n1 = 2*l1+1, n2 = 2*l2+1, n3 = 2*l3+1;
    double C[7][7][7] = {};
    for (int m1 = -l1; m1 <= l1; m1++)
        for (int m2 = -l2; m2 <= l2; m2++) {
            int m3 = m1 + m2;
            if (m3 >= -l3 && m3 <= l3)
                C[l1+m1][l2+m2][l3+m3] = su2_cg(l1, m1, l2, m2, l3, m3);
        }
    QT Q1 = make_q(l1), Q2 = make_q(l2), Q3 = make_q(l3);
    CD T1[7][7][7] = {};
    for (int j = 0; j < n1; j++)
        for (int k = 0; k < n2; k++)
            for (int m = 0; m < n3; m++) {
                double sr = 0, si = 0;
                for (int i = 0; i < n1; i++) {
                    double cv = C[i][k][m];
                    sr += Q1.q[i][j].re * cv;
                    si += Q1.q[i][j].im * cv;
                }
                T1[j][k][m] = {sr, si};
            }
    CD T2[7][7][7] = {};
    for (int j = 0; j < n1; j++)
        for (int l = 0; l < n2; l++)
            for (int m = 0; m < n3; m++) {
                double sr = 0, si = 0;
                for (int k = 0; k < n2; k++) {
                    CD a = Q2.q[k][l], b = T1[j][k][m];
                    sr += a.re*b.re - a.im*b.im;
                    si += a.re*b.im + a.im*b.re;
                }
                T2[j][l][m] = {sr, si};
            }
    double Cr[7][7][7] = {};
    double nrm2 = 0.0;
    for (int j = 0; j < n1; j++)
        for (int l = 0; l < n2; l++)
            for (int n = 0; n < n3; n++) {
                double s = 0;
                for (int m = 0; m < n3; m++) {
                    CD a = Q3.q[n][m], b = T2[j][l][m];
                    s += a.re*b.re + a.im*b.im;
                }
                Cr[j][l][n] = s;
                nrm2 += s * s;
            }
    double inv = 1.0 / csqrt(nrm2);
    Tab t{};
    for (int j = 0; j < n1; j++)
        for (int l = 0; l < n2; l++)
            for (int n = 0; n < n3; n++)
                t.v[(j*n2 + l)*n3 + n] = (float)(Cr[j][l][n] * inv);
    return t;
}

// 23 unique keys, lo-major, (la,lb)-lexicographic within lo (matches path order).
constexpr Tab T0  = make_w3j(0,0,0);
constexpr Tab T1_ = make_w3j(1,1,0);
constexpr Tab T2_ = make_w3j(2,2,0);
constexpr Tab T3_ = make_w3j(3,3,0);
constexpr Tab T4  = make_w3j(0,1,1);
constexpr Tab T5  = make_w3j(1,0,1);
constexpr Tab T6  = make_w3j(1,2,1);
constexpr Tab T7  = make_w3j(2,1,1);
constexpr Tab T8  = make_w3j(2,3,1);
constexpr Tab T9  = make_w3j(3,2,1);
constexpr Tab T10 = make_w3j(0,2,2);
constexpr Tab T11 = make_w3j(1,1,2);
constexpr Tab T12 = make_w3j(1,3,2);
constexpr Tab T13 = make_w3j(2,0,2);
constexpr Tab T14 = make_w3j(2,2,2);
constexpr Tab T15 = make_w3j(3,1,2);
constexpr Tab T16 = make_w3j(3,3,2);
constexpr Tab T17 = make_w3j(0,3,3);
constexpr Tab T18 = make_w3j(1,2,3);
constexpr Tab T19 = make_w3j(2,1,3);
constexpr Tab T20 = make_w3j(2,3,3);
constexpr Tab T21 = make_w3j(3,0,3);
constexpr Tab T22 = make_w3j(3,2,3);

constexpr int KLA[23]   = {0,1,2,3, 0,1,1,2,2,3, 0,1,1,2,2,3,3, 0,1,2,2,3,3};
constexpr int KLB[23]   = {0,1,2,3, 1,0,2,1,3,2, 2,1,3,0,2,1,3, 3,2,1,3,0,2};
constexpr int KLO[23]   = {0,0,0,0, 1,1,1,1,1,1, 2,2,2,2,2,2,2, 3,3,3,3,3,3};
// z-slot layout: keys 0-3 -> 1 slot, 4-9 -> 3, 10-16 -> 5, 17-22 -> 7.
constexpr int KZOFF[23] = {0,1,2,3, 4,7,10,13,16,19, 22,27,32,37,42,47,52, 57,64,71,78,85,92};

struct Term { int i, j, k; float w; };
struct TermList { Term t[1875]; int koff[24]; int n; };

constexpr TermList build_terms() {
    TermList L{};
    const Tab* ts[23] = {&T0,&T1_,&T2_,&T3_,&T4,&T5,&T6,&T7,&T8,&T9,&T10,&T11,
                         &T12,&T13,&T14,&T15,&T16,&T17,&T18,&T19,&T20,&T21,&T22};
    for (int key = 0; key < 23; key++) {
        L.koff[key] = L.n;
        const int la = KLA[key], lb = KLB[key], lo = KLO[key];
        const int n1 = 2*la+1, n2 = 2*lb+1, n3 = 2*lo+1;
        for (int i = 0; i < n1; i++)
            for (int j = 0; j < n2; j++)
                for (int k = 0; k < n3; k++) {
                    float w = ts[key]->v[(i*n2+j)*n3+k];
                    float aw = w < 0 ? -w : w;
                    if (aw > 1e-6f) {
                        L.t[L.n].i = la*la + i;
                        L.t[L.n].j = lb*lb + j;
                        L.t[L.n].k = KZOFF[key] + k;
                        L.t[L.n].w = w;
                        L.n++;
                    }
                }
    }
    L.koff[23] = L.n;
    return L;
}
constexpr TermList TL = build_terms();

// 8-way key-range split, balanced by term count (key granularity). Each of the
// 8 half-waves of phase 1 executes one range; key z-slots are disjoint.
constexpr int find_split(int target) {
    for (int k = 0; k <= 23; k++) if (TL.koff[k] >= target) return k;
    return 23;
}
constexpr int SP[9] = {0,
    find_split(TL.n * 1 / 8), find_split(TL.n * 2 / 8),
    find_split(TL.n * 3 / 8), find_split(TL.n * 4 / 8),
    find_split(TL.n * 5 / 8), find_split(TL.n * 6 / 8),
    find_split(TL.n * 7 / 8), 23};

} // namespace w3j_gen

// --- compile-time-unrolled sparse bilinear: per key, accumulate in registers,
// --- flush to the LDS z-row (all indices/coefs are compile-time constants).
template <int KEY, size_t... I>
__device__ __forceinline__ void term_unroll(float* __restrict__ acc,
                                            const float* __restrict__ xv,
                                            const float* __restrict__ yv,
                                            std::index_sequence<I...>) {
    constexpr int t0 = w3j_gen::TL.koff[KEY];
    ((acc[w3j_gen::TL.t[t0 + I].k - w3j_gen::KZOFF[KEY]] +=
          w3j_gen::TL.t[t0 + I].w * xv[w3j_gen::TL.t[t0 + I].i] * yv[w3j_gen::TL.t[t0 + I].j]), ...);
}

template <int KEY>
__device__ __forceinline__ void key_accum(float* __restrict__ zrow,
                                          const float* __restrict__ xv,
                                          const float* __restrict__ yv) {
    constexpr int n3 = 2 * w3j_gen::KLO[KEY] + 1;
    constexpr int nt = w3j_gen::TL.koff[KEY + 1] - w3j_gen::TL.koff[KEY];
    float acc[n3] = {};
    term_unroll<KEY>(acc, xv, yv, std::make_index_sequence<(size_t)nt>{});
    #pragma unroll
    for (int k = 0; k < n3; k++) zrow[w3j_gen::KZOFF[KEY] + k] = acc[k];
}

template <int FROM, size_t... K>
__device__ __forceinline__ void keys_range(float* __restrict__ zrow,
                                           const float* __restrict__ xv,
                                           const float* __restrict__ yv,
                                           std::index_sequence<K...>) {
    (key_accum<FROM + (int)K>(zrow, xv, yv), ...);
}

#define N_EDGES   65536
#define TILE      32
#define ZROW      108                 // padded row stride (16B-aligned)
#define ALL_BASE  75497472ull         // 65536 * 9 * 128

typedef float f32x4 __attribute__((ext_vector_type(4)));   // valid for nontemporal builtins

__device__ __forceinline__ float sigmoidf_(float v) { return 1.0f / (1.0f + __expf(-v)); }

__global__ __launch_bounds__(256, 3)
void cg_interaction_kernel(
    const float* __restrict__ x, const float* __restrict__ y,
    const float* __restrict__ w_cg, const float* __restrict__ b_cg,
    const float* __restrict__ w_all, const float* __restrict__ b_all,
    float* __restrict__ out)
{
    __shared__ __align__(16) float zs[TILE][ZROW];   // 13.8 KB

    const int tid = threadIdx.x;
    const int e0 = blockIdx.x * TILE;

    // ---- Phase 1: 8 half-wave groups x 32 edges; each group ~1/8 of terms ----
    {
        const int eidx = tid & 31;        // edge within tile
        const int esub = tid >> 5;        // 0..7 -> key-range
        float xv[16], yv[16];
        const float4* xp = (const float4*)(x + (size_t)(e0 + eidx) * 16);
        const float4* yp = (const float4*)(y + (size_t)(e0 + eidx) * 16);
        #pragma unroll
        for (int q = 0; q < 4; q++) {
            float4 v = xp[q];
            xv[4*q+0] = v.x; xv[4*q+1] = v.y; xv[4*q+2] = v.z; xv[4*q+3] = v.w;
            float4 u = yp[q];
            yv[4*q+0] = u.x; yv[4*q+1] = u.y; yv[4*q+2] = u.z; yv[4*q+3] = u.w;
        }
        using namespace w3j_gen;
        float* zrow = &zs[eidx][0];
        switch (esub) {
        case 0: keys_range<SP[0]>(zrow, xv, yv, std::make_index_sequence<SP[1]-SP[0]>{}); break;
        case 1: keys_range<SP[1]>(zrow, xv, yv, std::make_index_sequence<SP[2]-SP[1]>{}); break;
        case 2: keys_range<SP[2]>(zrow, xv, yv, std::make_index_sequence<SP[3]-SP[2]>{}); break;
        case 3: keys_range<SP[3]>(zrow, xv, yv, std::make_index_sequence<SP[4]-SP[3]>{}); break;
        case 4: keys_range<SP[4]>(zrow, xv, yv, std::make_index_sequence<SP[5]-SP[4]>{}); break;
        case 5: keys_range<SP[5]>(zrow, xv, yv, std::make_index_sequence<SP[6]-SP[5]>{}); break;
        case 6: keys_range<SP[6]>(zrow, xv, yv, std::make_index_sequence<SP[7]-SP[6]>{}); break;
        default: keys_range<SP[7]>(zrow, xv, yv, std::make_index_sequence<SP[8]-SP[7]>{}); break;
        }
    }
    __syncthreads();

    // ---- Phase 2: 32 channel-quads x 8 edge-slots x 4 edges each ----
    const int cq = (tid & 31) << 2;   // channel base: 0,4,...,124
    const int es = tid >> 5;          // edge slot 0..7

    float w00[4][4], wg1[4][4], wg2[4][4];
    #pragma unroll
    for (int p = 0; p < 4; p++) {
        float4 a = *(const float4*)(w_cg + p * 128 + cq);
        w00[p][0]=a.x; w00[p][1]=a.y; w00[p][2]=a.z; w00[p][3]=a.w;
        float4 b = *(const float4*)(w_cg + 512 + p * 256 + cq);
        wg1[p][0]=b.x; wg1[p][1]=b.y; wg1[p][2]=b.z; wg1[p][3]=b.w;
        float4 d = *(const float4*)(w_cg + 640 + p * 256 + cq);
        wg2[p][0]=d.x; wg2[p][1]=d.y; wg2[p][2]=d.z; wg2[p][3]=d.w;
    }
    float wl1[6][4];
    #pragma unroll
    for (int p = 0; p < 6; p++) {
        float4 a = *(const float4*)(w_cg + 1536 + p * 128 + cq);
        wl1[p][0]=a.x; wl1[p][1]=a.y; wl1[p][2]=a.z; wl1[p][3]=a.w;
    }
    float wl2[7][4];
    #pragma unroll
    for (int p = 0; p < 7; p++) {
        float4 a = *(const float4*)(w_cg + 2304 + p * 128 + cq);
        wl2[p][0]=a.x; wl2[p][1]=a.y; wl2[p][2]=a.z; wl2[p][3]=a.w;
    }
    float b0[4], b1[4], b2[4];
    {
        float4 a = *(const float4*)(b_cg + cq);
        b0[0]=a.x; b0[1]=a.y; b0[2]=a.z; b0[3]=a.w;
        float4 b = *(const float4*)(b_cg + 128 + cq);
        b1[0]=b.x; b1[1]=b.y; b1[2]=b.z; b1[3]=b.w;
        float4 d = *(const float4*)(b_cg + 256 + cq);
        b2[0]=d.x; b2[1]=d.y; b2[2]=d.z; b2[3]=d.w;
    }

    const float SQ12 = 0.70710678118654752f;   // sqrt(3/6)
    const float SQ57 = 0.84515425472851657f;   // sqrt(5/7)

    float* o = out + (size_t)(e0 + es) * 1152 + cq;
    for (int t = es; t < TILE; t += 8, o += 8 * 1152) {
        const float* zrow = &zs[t][0];

        // chunk A: z[0..3] -> scalar row + gates
        float4 z03 = *(const float4*)zrow;
        float sc[4], g1[4], g2[4];
        #pragma unroll
        for (int j = 0; j < 4; j++) {
            float u0 = (z03.x*w00[0][j] + z03.y*w00[1][j] + z03.z*w00[2][j] + z03.w*w00[3][j]) * 0.5f + b0[j];
            float u1 = (z03.x*wg1[0][j] + z03.y*wg1[1][j] + z03.z*wg1[2][j] + z03.w*wg1[3][j]) * 0.5f + b1[j];
            float u2 = (z03.x*wg2[0][j] + z03.y*wg2[1][j] + z03.z*wg2[2][j] + z03.w*wg2[3][j]) * 0.5f + b2[j];
            sc[j] = u0 * sigmoidf_(u0);
            g1[j] = sigmoidf_(u1) * SQ12;
            g2[j] = sigmoidf_(u2) * SQ57;
        }
        f32x4 r0 = { sc[0], sc[1], sc[2], sc[3] };
        __builtin_nontemporal_store(r0, (f32x4*)o);

        // chunk B: z[4..23] -> l=1 rows (z[4+3p+k] = zl[3p+k])
        float zl[20];
        #pragma unroll
        for (int q = 0; q < 5; q++) {
            float4 v = *(const float4*)(zrow + 4 + 4 * q);
            zl[4*q+0] = v.x; zl[4*q+1] = v.y; zl[4*q+2] = v.z; zl[4*q+3] = v.w;
        }
        #pragma unroll
        for (int k = 0; k < 3; k++) {
            float s[4];
            #pragma unroll
            for (int j = 0; j < 4; j++) {
                float a = 0.0f;
                #pragma unroll
                for (int p = 0; p < 6; p++) a += zl[3*p + k] * wl1[p][j];
                s[j] = a * g1[j];
            }
            f32x4 r = { s[0], s[1], s[2], s[3] };
            __builtin_nontemporal_store(r, (f32x4*)(o + (1 + k) * 128));
        }

        // chunk C: z[22..56] -> l=2 rows (z[22+5p+k] = zh[5p+k])
        float zh[35];
        zh[0] = zl[18]; zh[1] = zl[19];            // z22, z23
        #pragma unroll
        for (int q = 0; q < 8; q++) {
            float4 v = *(const float4*)(zrow + 24 + 4 * q);
            zh[2+4*q+0] = v.x; zh[2+4*q+1] = v.y; zh[2+4*q+2] = v.z; zh[2+4*q+3] = v.w;
        }
        zh[34] = zrow[56];
        #pragma unroll
        for (int k = 0; k < 5; k++) {
            float s[4];
            #pragma unroll
            for (int j = 0; j < 4; j++) {
                float a = 0.0f;
                #pragma unroll
                for (int p = 0; p < 7; p++) a += zh[5*p + k] * wl2[p][j];
                s[j] = a * g2[j];
            }
            f32x4 r = { s[0], s[1], s[2], s[3] };
            __builtin_nontemporal_store(r, (f32x4*)(o + (4 + k) * 128));
        }
    }

    // ---- cg_all tail: 16 outputs/edge, threads 0..127 (c = tid&15, 8 edge-slots) ----
    if (tid < 128) {
        const int c = tid & 15;
        const int es2 = tid >> 4;     // 0..7
        const float SQ76 = 1.08012344973464f;  // sqrt(7/6)

        if (c == 0) {
            const float gw0 = w_all[0], gw1 = w_all[1], gw2 = w_all[2], gw3 = w_all[3], gb = b_all[0];
            for (int t = es2; t < TILE; t += 8) {
                const float* zr = &zs[t][0];
                float g = (zr[0]*gw0 + zr[1]*gw1 + zr[2]*gw2 + zr[3]*gw3) * 0.5f + gb;
                __builtin_nontemporal_store(g * sigmoidf_(g), out + ALL_BASE + (size_t)(e0 + t) * 16);
            }
        } else if (c < 4) {
            const float gw0 = w_all[4], gw1 = w_all[7], gw2 = w_all[10], gw3 = w_all[13], gb = b_all[1];
            float aw[6];
            #pragma unroll
            for (int p = 0; p < 6; p++) aw[p] = w_all[16 + p];
            const int zb = 4 + (c - 1);
            for (int t = es2; t < TILE; t += 8) {
                const float* zr = &zs[t][0];
                float g = (zr[0]*gw0 + zr[1]*gw1 + zr[2]*gw2 + zr[3]*gw3) * 0.5f + gb;
                float s = 0.0f;
                #pragma unroll
                for (int p = 0; p < 6; p++) s += aw[p] * zr[zb + 3*p];
                __builtin_nontemporal_store(s * SQ12 * sigmoidf_(g),
                                            out + ALL_BASE + (size_t)(e0 + t) * 16 + c);
            }
        } else if (c < 9) {
            const float gw0 = w_all[5], gw1 = w_all[8], gw2 = w_all[11], gw3 = w_all[14], gb = b_all[2];
            float aw[7];
            #pragma unroll
            for (int p = 0; p < 7; p++) aw[p] = w_all[22 + p];
            const int zb = 22 + (c - 4);
            for (int t = es2; t < TILE; t += 8) {
                const float* zr = &zs[t][0];
                float g = (zr[0]*gw0 + zr[1]*gw1 + zr[2]*gw2 + zr[3]*gw3) * 0.5f + gb;
                float s = 0.0f;
                #pragma unroll
                for (int p = 0; p < 7; p++) s += aw[p] * zr[zb + 5*p];
                __builtin_nontemporal_store(s * SQ57 * sigmoidf_(g),
                                            out + ALL_BASE + (size_t)(e0 + t) * 16 + c);
            }
        } else {
            const float gw0 = w_all[6], gw1 = w_all[9], gw2 = w_all[12], gw3 = w_all[15], gb = b_all[3];
            float aw[6];
            #pragma unroll
            for (int p = 0; p < 6; p++) aw[p] = w_all[29 + p];
            const int zb = 57 + (c - 9);
            for (int t = es2; t < TILE; t += 8) {
                const float* zr = &zs[t][0];
                float g = (zr[0]*gw0 + zr[1]*gw1 + zr[2]*gw2 + zr[3]*gw3) * 0.5f + gb;
                float s = 0.0f;
                #pragma unroll
                for (int p = 0; p < 6; p++) s += aw[p] * zr[zb + 7*p];
                __builtin_nontemporal_store(s * SQ76 * sigmoidf_(g),
                                            out + ALL_BASE + (size_t)(e0 + t) * 16 + c);
            }
        }
    }
}

extern "C" void kernel_launch(void* const* d_in, const int* in_sizes, int n_in,
                              void* d_out, int out_size, void* d_ws, size_t ws_size,
                              hipStream_t stream) {
    const float* x     = (const float*)d_in[0];
    const float* y     = (const float*)d_in[1];
    const float* w_cg  = (const float*)d_in[2];
    const float* b_cg  = (const float*)d_in[3];
    const float* w_all = (const float*)d_in[4];
    const float* b_all = (const float*)d_in[5];
    float* out = (float*)d_out;

    dim3 grid(N_EDGES / TILE), block(256);
    hipLaunchKernelGGL(cg_interaction_kernel, grid, block, 0, stream,
                       x, y, w_cg, b_cg, w_all, b_all, out);
}